// Round 12
// baseline (96.083 us; speedup 1.0000x reference)
//
#include <hip/hip_runtime.h>
#include <math.h>

typedef unsigned long long u64;
typedef unsigned int u32;
typedef unsigned short u16;
typedef unsigned char u8;

#define N_NODES    50000
#define N_G_EDGES  400000
#define N_LG_EDGES 600000
#define OUT_FEATS  64
#define EPSV       0.001f
#define PI_F       3.14159265358979323846f
#define HPI_F      1.57079632679489662f
#define FXSCALE    512.0f
#define INV_FXSCALE (1.0f/512.0f)

#define NBLK 256
#define NTHR 1024

#define WID   1564          // ls-bucket width; 256*1564 = 400384 >= 400000
#define EPB1  2344          // edges per sort block; 256*2344 = 600064 >= 600000
#define NPB   196           // nodes per node-bucket
#define SPB   (NPB*4)       // 784 slots
#define CAP2  2816          // per-block mrec capacity (~2344 + 9.8 sigma)

// g-histogram: 16 chunks x 16 ranges (block b: cc=b&15, r=b>>4)
#define GH_EPC 25000
#define GH_BR  3125
#define GH_W   784
#define PK_GPB 1563         // kk8 pack slice; 256*1563 = 400128

// ws layout (bytes):
//   kk8        u8 [400000]      @ 0          (  400,000)
//   cg         u32[256*784]     @ 400,000    (  802,816)
//   prefT1     u32[256*257]     @ 1,202,816  (  263,168)
//   prefT2     u32[256*257]     @ 1,465,984  (  263,168)
//   srecs_meta u32[256*2344]    @ 1,729,152  (2,400,256)
//   srecs_ct   u32[256*2344]    @ 4,129,408  (2,400,256)
//   srecs_dn   u32[256*2344]    @ 6,529,664  (2,400,256)
//   mq_lo      u32[256*2816]    @ 8,929,920  (2,883,584)
//   mq_hi      u32[256*2816]    @ 11,813,504 (2,883,584)
//   mslot      u32[256*2816]    @ 14,697,088 (2,883,584)
// total 17,580,672

__device__ u32 g_bar_cnt = 0;
__device__ u32 g_bar_sense = 0;

// R7 lesson: NEVER spin on an ACQUIRE load (per-poll buffer_inv storm).
// Poll RELAXED (coherence-point load, no cache maintenance) + s_sleep;
// fence ONCE on each side. Last arrival resets counter BEFORE release-storing
// the sense (release orders the reset ahead of the flip -> replay-safe).
__device__ __forceinline__ void grid_sync(u32* my_sense) {
    __syncthreads();
    if (threadIdx.x == 0) {
        u32 want = *my_sense ^ 1u;
        __threadfence();   // make this block's writes visible device-wide
        u32 old = __hip_atomic_fetch_add(&g_bar_cnt, 1u, __ATOMIC_RELAXED,
                                         __HIP_MEMORY_SCOPE_AGENT);
        if (old == NBLK - 1) {
            __hip_atomic_store(&g_bar_cnt, 0u, __ATOMIC_RELAXED,
                               __HIP_MEMORY_SCOPE_AGENT);
            __hip_atomic_store(&g_bar_sense, want, __ATOMIC_RELEASE,
                               __HIP_MEMORY_SCOPE_AGENT);
        } else {
            int spins = 0;
            while (__hip_atomic_load(&g_bar_sense, __ATOMIC_RELAXED,
                                     __HIP_MEMORY_SCOPE_AGENT) != want) {
                __builtin_amdgcn_s_sleep(16);
                if (++spins > (1 << 20)) break;   // fail visibly, never hang
            }
        }
        *my_sense = want;
        __threadfence();   // acquire side: drop stale cached copies, once
    }
    __syncthreads();
}

__global__ __launch_bounds__(NTHR) void fused_v2(
    const int* __restrict__ an, const int* __restrict__ gsrc,
    const int* __restrict__ gdst, const int* __restrict__ lgsrc,
    const int* __restrict__ lgdst, const float* __restrict__ costheta,
    const float* __restrict__ dnr, const float* __restrict__ pa,
    const float* __restrict__ pb, const float* __restrict__ pc,
    const float* __restrict__ pd, const float* __restrict__ VT,
    u8* __restrict__ kk8, u32* __restrict__ cg,
    u32* __restrict__ prefT1, u32* __restrict__ prefT2,
    u32* __restrict__ sme, u32* __restrict__ sct, u32* __restrict__ sdn,
    u32* __restrict__ mqlo, u32* __restrict__ mqhi, u32* __restrict__ mslot,
    float* __restrict__ out)
{
    __shared__ __align__(16) u32 smem[12608];   // 50.4 KB union
    const int tid = threadIdx.x;
    const int bid = blockIdx.x;
    u32 my_sense = __hip_atomic_load(&g_bar_sense, __ATOMIC_RELAXED,
                                     __HIP_MEMORY_SCOPE_AGENT);

    // ================= P1: ls-bucket sort + g-hist + kk8 pack =================
    {
        u32* metaS = smem;            // [2344]
        u32* ctS   = smem + 2344;     // [2344]
        u32* dnS   = smem + 4688;     // [2344]
        u32* lcnt  = smem + 7032;     // [256]
        u32* pref  = smem + 7288;     // [257]

        if (tid < 256) lcnt[tid] = 0u;
        __syncthreads();

        const int e0 = bid * EPB1;
        const int e1 = (e0 + EPB1 < N_LG_EDGES) ? e0 + EPB1 : N_LG_EDGES;
        u32 pw[3], cv[3], dv[3], mv[3];
#pragma unroll
        for (int it = 0; it < 3; ++it) {
            mv[it] = 0u;
            int e = e0 + it * NTHR + tid;
            if (e < e1) {
                int ls = lgsrc[e];
                int ld = lgdst[e];
                cv[it] = __float_as_uint(costheta[e]);
                dv[it] = __float_as_uint(dnr[e]);
                u32 bk = (u32)ls / WID;
                u32 li = (u32)ls - bk * WID;
                pw[it] = ((u32)ld << 11) | li;
                u32 rank = atomicAdd(&lcnt[bk], 1u);
                mv[it] = 0x80000000u | (rank << 8) | bk;
            }
        }
        __syncthreads();
        if (tid < 256) pref[tid + 1] = lcnt[tid];
        if (tid == 0) pref[0] = 0u;
        __syncthreads();
        for (int off = 1; off < 256; off <<= 1) {
            u32 add = 0;
            if (tid < 256 && tid >= off) add = pref[tid - off + 1];
            __syncthreads();
            if (tid < 256) pref[tid + 1] += add;
            __syncthreads();
        }
#pragma unroll
        for (int it = 0; it < 3; ++it) {
            if (mv[it] & 0x80000000u) {
                u32 bk = mv[it] & 0xffu;
                u32 pos = pref[bk] + ((mv[it] >> 8) & 0x7fffffu);
                metaS[pos] = pw[it]; ctS[pos] = cv[it]; dnS[pos] = dv[it];
            }
        }
        __syncthreads();
        const u32 btot = pref[256];
        for (u32 i = tid; i < btot; i += NTHR) {
            sme[(size_t)bid * EPB1 + i] = metaS[i];
            sct[(size_t)bid * EPB1 + i] = ctS[i];
            sdn[(size_t)bid * EPB1 + i] = dnS[i];
        }
        if (tid <= 256) prefT1[bid * 257 + tid] = pref[tid];
        __syncthreads();

        // ---- g-histogram: chunk cc = bid&15, bin range r = bid>>4 ----
        u32* hist = smem;   // [784], reuse after sync
        for (int w = tid; w < GH_W; w += NTHR) hist[w] = 0u;
        __syncthreads();
        {
            const int cc = bid & 15;
            const int lo = (bid >> 4) * GH_BR;
            const int s0 = cc * GH_EPC;
            for (int g = s0 + tid; g < s0 + GH_EPC; g += NTHR) {
                unsigned lb = (unsigned)(gsrc[g] - lo);
                if (lb < (unsigned)GH_BR)
                    atomicAdd(&hist[lb >> 2], 1u << (8 * (lb & 3)));
            }
        }
        __syncthreads();
        for (int w = tid; w < GH_W; w += NTHR) cg[bid * GH_W + w] = hist[w];

        // ---- kk8 pack slice ----
        const int g0 = bid * PK_GPB;
        const int g1 = (g0 + PK_GPB < N_G_EDGES) ? g0 + PK_GPB : N_G_EDGES;
        for (int g = g0 + tid; g < g1; g += NTHR)
            kk8[g] = (u8)(an[gsrc[g]] | (an[gdst[g]] << 4));
    }

    grid_sync(&my_sense);

    // ================= P2: per ls-window compute + node-bucket sort ===========
    {
        u32* cntinv = smem;            // [1564] counts -> inv floats in place
        u32* nkw    = smem + 1564;     // [1564] node | kk<<16
        u32* sstart = smem + 3128;     // [256]
        u32* spref  = smem + 3384;     // [257]
        u32* lcnt2  = smem + 3641;     // [256]
        u32* pref2  = smem + 3897;     // [257] (3897+257=4154, pad to 4160)
        u32* rQlo   = smem + 4160;     // [2816]
        u32* rQhi   = smem + 6976;     // [2816]
        u32* rSl    = smem + 9792;     // [2816]
        const int b = bid;
        const int lo = b * WID;

        for (int i = tid; i < WID; i += NTHR) cntinv[i] = 0u;
        if (tid < 256) {
            u32 a = prefT1[tid * 257 + b];
            u32 c2 = prefT1[tid * 257 + b + 1];
            sstart[tid] = a; spref[tid + 1] = c2 - a; lcnt2[tid] = 0u;
        }
        if (tid == 0) spref[0] = 0u;
        __syncthreads();
        for (int off = 1; off < 256; off <<= 1) {
            u32 add = 0;
            if (tid < 256 && tid >= off) add = spref[tid - off + 1];
            __syncthreads();
            if (tid < 256) spref[tid + 1] += add;
            __syncthreads();
        }
        const u32 total = spref[256];

        // pass 1: per-ls counts from this bucket's own records
        for (u32 i = tid; i < total; i += NTHR) {
            int l2 = 0, h2 = 256;
            while (h2 - l2 > 1) {
                int mid = (l2 + h2) >> 1;
                if (spref[mid] <= i) l2 = mid; else h2 = mid;
            }
            u32 pwv = sme[(size_t)l2 * EPB1 + sstart[l2] + (i - spref[l2])];
            atomicAdd(&cntinv[pwv & 0x7ffu], 1u);
        }
        // window info (coalesced)
        for (int i = tid; i < WID; i += NTHR) {
            int ls = lo + i;
            u32 nk = 0u;
            if (ls < N_G_EDGES)
                nk = (u32)(u16)gsrc[ls] | ((u32)kk8[ls] << 16);
            nkw[i] = nk;
        }
        __syncthreads();
        for (int i = tid; i < WID; i += NTHR) {
            u32 c = cntinv[i];
            cntinv[i] = __float_as_uint(1.0f / (float)(c < 1u ? 1u : c));
        }
        __syncthreads();

        // Taylor coeffs (R9/R10/R11-proven)
        float A0[4], A1[4], A2[4], DD[4];
#pragma unroll
        for (int h = 0; h < 4; ++h) {
            float a = pa[h], B = fmodf(pb[h], PI_F), c = pc[h], d = pd[h];
            float K = a * HPI_F + B;
            float ck = cosf(K), sk = sinf(K);
            float u0 = 0.5f * (1.0f + ck);
            float f0 = powf(u0, c);
            float g1v = (-0.5f * a * sk) / u0;
            float u2 = -0.25f * a * a * ck;
            float g2v = u2 / u0 - 0.5f * g1v * g1v;
            A0[h] = f0;
            A1[h] = f0 * c * g1v;
            A2[h] = f0 * (c * g2v + 0.5f * c * c * g1v * g1v);
            DD[h] = d;
        }

        u64 qv[3]; u32 mv2[3];
#pragma unroll
        for (int it = 0; it < 3; ++it) {
            mv2[it] = 0u;
            u32 i = (u32)(it * NTHR + tid);
            if (i < total) {
                int l2 = 0, h2 = 256;
                while (h2 - l2 > 1) {
                    int mid = (l2 + h2) >> 1;
                    if (spref[mid] <= i) l2 = mid; else h2 = mid;
                }
                size_t idx = (size_t)l2 * EPB1 + sstart[l2] + (i - spref[l2]);
                u32 pwv = sme[idx];
                float ct = __uint_as_float(sct[idx]);
                float dn = __uint_as_float(sdn[idx]);
                u32 li = pwv & 0x7ffu;
                u32 ld = pwv >> 11;
                float inv = __uint_as_float(cntinv[li]);
                u32 nk = nkw[li];
                int node = (int)(nk & 0xffffu);
                u32 kw = (nk >> 16) & 0xffu;
                int ka = (int)(kw & 0xfu);
                int kb = (int)(kw >> 4);
                int kd = kk8[ld] >> 4;
                int key = ((ka == kd) ? 2 : 0) + ((kb == ka && kb == kd) ? 1 : 0);
                ct = fminf(fmaxf(ct, -EPSV), EPSV);
                float del = -ct;
                float dn2 = dn * dn;
                float s = inv * FXSCALE;
                u64 q = 0;
#pragma unroll
                for (int h = 0; h < 4; ++h) {
                    float ang = A0[h] + del * (A1[h] + del * A2[h]);
                    float rad = __expf(-DD[h] * dn2);
                    q |= (u64)(u32)(ang * rad * s + 0.5f) << (16 * h);
                }
                u32 nb = (u32)node / NPB;
                u32 slot = ((u32)node - nb * NPB) * 4u + (u32)key;
                u32 rank = atomicAdd(&lcnt2[nb], 1u);
                qv[it] = q;
                mv2[it] = 0x80000000u | (rank << 18) | (nb << 10) | slot;
            }
        }
        __syncthreads();
        if (tid < 256) pref2[tid + 1] = lcnt2[tid];
        if (tid == 0) pref2[0] = 0u;
        __syncthreads();
        for (int off = 1; off < 256; off <<= 1) {
            u32 add = 0;
            if (tid < 256 && tid >= off) add = pref2[tid - off + 1];
            __syncthreads();
            if (tid < 256) pref2[tid + 1] += add;
            __syncthreads();
        }
#pragma unroll
        for (int it = 0; it < 3; ++it) {
            if (mv2[it] & 0x80000000u) {
                u32 nb = (mv2[it] >> 10) & 0xffu;
                u32 pos = pref2[nb] + ((mv2[it] >> 18) & 0x1fffu);
                if (pos < CAP2) {
                    rQlo[pos] = (u32)qv[it];
                    rQhi[pos] = (u32)(qv[it] >> 32);
                    rSl[pos] = mv2[it] & 0x3ffu;
                }
            }
        }
        __syncthreads();
        u32 t2 = pref2[256]; if (t2 > CAP2) t2 = CAP2;
        for (u32 i = tid; i < t2; i += NTHR) {
            mqlo[(size_t)b * CAP2 + i] = rQlo[i];
            mqhi[(size_t)b * CAP2 + i] = rQhi[i];
            mslot[(size_t)b * CAP2 + i] = rSl[i];
        }
        if (tid <= 256) {
            u32 v = pref2[tid];
            prefT2[b * 257 + tid] = (v < CAP2) ? v : CAP2;
        }
    }

    grid_sync(&my_sense);

    // ================= P3: per node-bucket gather + output ====================
    {
        u64* ts      = (u64*)smem;            // [784] (smem 16B-aligned)
        float* vt_s  = (float*)(smem + 1568); // [1024]
        float* ivg   = (float*)(smem + 2592); // [196]
        u32* sstart  = smem + 2788;           // [256]
        u32* spref   = smem + 3044;           // [257]
        const int nb = bid;

        for (int i = tid; i < SPB; i += NTHR) ts[i] = 0ull;
        vt_s[tid] = VT[tid];
        if (tid < NPB) {
            int n = nb * NPB + tid;
            float iv = 0.0f;
            if (n < N_NODES) {
                int r = n / GH_BR, lb = n - r * GH_BR;
                int w = lb >> 2, sh = 8 * (lb & 3);
                u32 c = 0;
#pragma unroll
                for (int cc = 0; cc < 16; ++cc)
                    c += (cg[((r << 4) + cc) * GH_W + w] >> sh) & 0xffu;
                iv = 1.0f / (float)(c < 1u ? 1u : c);
            }
            ivg[tid] = iv;
        }
        if (tid < 256) {
            u32 a = prefT2[tid * 257 + nb];
            u32 c2 = prefT2[tid * 257 + nb + 1];
            sstart[tid] = a; spref[tid + 1] = c2 - a;
        }
        if (tid == 0) spref[0] = 0u;
        __syncthreads();
        for (int off = 1; off < 256; off <<= 1) {
            u32 add = 0;
            if (tid < 256 && tid >= off) add = spref[tid - off + 1];
            __syncthreads();
            if (tid < 256) spref[tid + 1] += add;
            __syncthreads();
        }
        const u32 total = spref[256];

        for (u32 i = tid; i < total; i += NTHR) {
            int l2 = 0, h2 = 256;
            while (h2 - l2 > 1) {
                int mid = (l2 + h2) >> 1;
                if (spref[mid] <= i) l2 = mid; else h2 = mid;
            }
            size_t idx = (size_t)l2 * CAP2 + sstart[l2] + (i - spref[l2]);
            u64 q = (u64)mqlo[idx] | ((u64)mqhi[idx] << 32);
            atomicAdd(&ts[mslot[idx]], q);
        }
        __syncthreads();

        const int n0 = nb * NPB;
        for (int j = tid; j < NPB * OUT_FEATS; j += NTHR) {
            int nl = j >> 6, f = j & 63;
            int n = n0 + nl;
            if (n < N_NODES) {
                float acc = 0.0f;
#pragma unroll
                for (int k = 0; k < 4; ++k) {
                    u64 t = ts[nl * 4 + k];
#pragma unroll
                    for (int h = 0; h < 4; ++h) {
                        float tv = (float)((u32)(t >> (16 * h)) & 0xffffu);
                        acc += vt_s[k * 256 + f * 4 + h] * tv;
                    }
                }
                out[n * OUT_FEATS + f] = acc * INV_FXSCALE * ivg[nl];
            }
        }
    }
}

extern "C" void kernel_launch(void* const* d_in, const int* in_sizes, int n_in,
                              void* d_out, int out_size, void* d_ws, size_t ws_size,
                              hipStream_t stream) {
    const int*   an       = (const int*)d_in[0];
    const int*   gsrc     = (const int*)d_in[1];
    const int*   gdst     = (const int*)d_in[2];
    const int*   lgsrc    = (const int*)d_in[3];
    const int*   lgdst    = (const int*)d_in[4];
    const float* costheta = (const float*)d_in[5];
    const float* dnr      = (const float*)d_in[6];
    const float* pa       = (const float*)d_in[7];
    const float* pb       = (const float*)d_in[8];
    const float* pc       = (const float*)d_in[9];
    const float* pd       = (const float*)d_in[10];
    const float* vt       = (const float*)d_in[11];
    float* out = (float*)d_out;

    char* ws = (char*)d_ws;
    u8*  kk8    = (u8*) (ws + 0);
    u32* cg     = (u32*)(ws + 400000);
    u32* prefT1 = (u32*)(ws + 1202816);
    u32* prefT2 = (u32*)(ws + 1465984);
    u32* sme    = (u32*)(ws + 1729152);
    u32* sct    = (u32*)(ws + 4129408);
    u32* sdn    = (u32*)(ws + 6529664);
    u32* mqlo   = (u32*)(ws + 8929920);
    u32* mqhi   = (u32*)(ws + 11813504);
    u32* mslot  = (u32*)(ws + 14697088);

    fused_v2<<<dim3(NBLK), dim3(NTHR), 0, stream>>>(
        an, gsrc, gdst, lgsrc, lgdst, costheta, dnr, pa, pb, pc, pd, vt,
        kk8, cg, prefT1, prefT2, sme, sct, sdn, mqlo, mqhi, mslot, out);
}

// Round 13
// 51.406 us; speedup vs baseline: 1.8691x; 1.8691x over previous
//
#include <hip/hip_runtime.h>
#include <math.h>

typedef unsigned long long u64;
typedef unsigned int u32;
typedef unsigned short u16;
typedef unsigned char u8;

#define N_NODES    50000
#define N_G_EDGES  400000
#define N_LG_EDGES 600000
#define OUT_FEATS  64
#define EPSV       0.001f
#define PI_F       3.14159265358979323846f
#define HPI_F      1.57079632679489662f
#define FXSCALE    512.0f
#define INV_FXSCALE (1.0f/512.0f)

// ---- k1 roles (384 blocks) ----
#define SB_N    256        // [0,256): ls-bucket sort
#define EPB1    2344       // 256*2344 = 600064 >= 600000
#define GH_B0   256        // [256,272): g histogram, 16 chunks, full 50k range
#define GH_N    16
#define GH_EPC  25000
#define GH_W    12500
#define PK_B0   272        // [272,384): kk8 pack
#define PK_GPB  3572       // 112*3572 = 400064
#define K1_GRID 384

#define WID   1564         // ls-bucket width; 256*1564 >= 400000
#define NPB   196          // nodes per node-bucket
#define SPB   (NPB*4)
#define CAP2  2816

// ws layout (bytes):
//   kk8    u8 [400000]    @ 0          (  400,000)
//   cg     u32[16*12500]  @ 400,000    (  800,000)
//   prefT1 u32[256*257]   @ 1,200,000  (  263,168)
//   prefT2 u32[256*257]   @ 1,463,168  (  263,168)
//   sme    u32[256*2344]  @ 1,726,336  (2,400,256)
//   sct    u32[256*2344]  @ 4,126,592  (2,400,256)
//   sdn    u32[256*2344]  @ 6,526,848  (2,400,256)
//   mqlo   u32[256*2816]  @ 8,927,104  (2,883,584)
//   mqhi   u32[256*2816]  @ 11,810,688 (2,883,584)
//   mslot  u32[256*2816]  @ 14,694,272 (2,883,584)
// total 17,577,856

// ============ k1: ls-bucket sort (nt streams) + g-hist + kk8 pack ============
__global__ __launch_bounds__(1024) void k1(const int* __restrict__ an,
                                           const int* __restrict__ gsrc,
                                           const int* __restrict__ gdst,
                                           const int* __restrict__ lgsrc,
                                           const int* __restrict__ lgdst,
                                           const float* __restrict__ costheta,
                                           const float* __restrict__ dnr,
                                           u8*  __restrict__ kk8,
                                           u32* __restrict__ cg,
                                           u32* __restrict__ prefT1,
                                           u32* __restrict__ sme,
                                           u32* __restrict__ sct,
                                           u32* __restrict__ sdn) {
    __shared__ u32 smem[12500];   // 50 KB union
    const int tid = threadIdx.x;
    const int bid = blockIdx.x;

    if (bid < SB_N) {
        u32* metaS = smem;            // [2344]
        u32* ctS   = smem + 2344;     // [2344]
        u32* dnS   = smem + 4688;     // [2344]
        u32* lcnt  = smem + 7032;     // [256]
        u32* pref  = smem + 7288;     // [257]
        if (tid < 256) lcnt[tid] = 0u;
        __syncthreads();

        const int e0 = bid * EPB1;
        const int e1 = (e0 + EPB1 < N_LG_EDGES) ? e0 + EPB1 : N_LG_EDGES;
        u32 pw[3], cv[3], dv[3], mv[3];
#pragma unroll
        for (int it = 0; it < 3; ++it) {
            mv[it] = 0u;
            int e = e0 + it * 1024 + tid;
            if (e < e1) {
                int ls = __builtin_nontemporal_load(&lgsrc[e]);
                int ld = __builtin_nontemporal_load(&lgdst[e]);
                cv[it] = __float_as_uint(__builtin_nontemporal_load(&costheta[e]));
                dv[it] = __float_as_uint(__builtin_nontemporal_load(&dnr[e]));
                u32 bk = (u32)ls / WID;
                u32 li = (u32)ls - bk * WID;
                pw[it] = ((u32)ld << 11) | li;
                u32 rank = atomicAdd(&lcnt[bk], 1u);
                mv[it] = 0x80000000u | (rank << 8) | bk;
            }
        }
        __syncthreads();
        if (tid < 256) pref[tid + 1] = lcnt[tid];
        if (tid == 0) pref[0] = 0u;
        __syncthreads();
        for (int off = 1; off < 256; off <<= 1) {
            u32 add = 0;
            if (tid < 256 && tid >= off) add = pref[tid - off + 1];
            __syncthreads();
            if (tid < 256) pref[tid + 1] += add;
            __syncthreads();
        }
#pragma unroll
        for (int it = 0; it < 3; ++it) {
            if (mv[it] & 0x80000000u) {
                u32 bk = mv[it] & 0xffu;
                u32 pos = pref[bk] + ((mv[it] >> 8) & 0x7fffffu);
                metaS[pos] = pw[it]; ctS[pos] = cv[it]; dnS[pos] = dv[it];
            }
        }
        __syncthreads();
        const u32 btot = pref[256];
        for (u32 i = tid; i < btot; i += 1024) {
            __builtin_nontemporal_store(metaS[i], &sme[(size_t)bid * EPB1 + i]);
            __builtin_nontemporal_store(ctS[i],   &sct[(size_t)bid * EPB1 + i]);
            __builtin_nontemporal_store(dnS[i],   &sdn[(size_t)bid * EPB1 + i]);
        }
        if (tid <= 256) prefT1[bid * 257 + tid] = pref[tid];
    } else if (bid < PK_B0) {
        // g histogram: chunk cc, full 50k-bin range, u8-packed
        const int cc = bid - GH_B0;
        for (int w = tid; w < GH_W; w += 1024) smem[w] = 0u;
        __syncthreads();
        const int s0 = cc * GH_EPC;
        for (int g = s0 + tid; g < s0 + GH_EPC; g += 1024) {
            int n = gsrc[g];
            atomicAdd(&smem[n >> 2], 1u << (8 * (n & 3)));
        }
        __syncthreads();
        for (int w = tid; w < GH_W; w += 1024) cg[cc * GH_W + w] = smem[w];
    } else {
        const int g0 = (bid - PK_B0) * PK_GPB;
        const int g1 = (g0 + PK_GPB < N_G_EDGES) ? g0 + PK_GPB : N_G_EDGES;
        for (int g = g0 + tid; g < g1; g += 1024)
            kk8[g] = (u8)(an[gsrc[g]] | (an[gdst[g]] << 4));
    }
}

// ============ k2: window compute + node-bucket sort (kk8 gather stays cached) ============
__global__ __launch_bounds__(1024) void k2(const int* __restrict__ gsrc,
                                           const u8*  __restrict__ kk8,
                                           const u32* __restrict__ prefT1,
                                           const u32* __restrict__ sme,
                                           const u32* __restrict__ sct,
                                           const u32* __restrict__ sdn,
                                           const float* __restrict__ pa,
                                           const float* __restrict__ pb,
                                           const float* __restrict__ pc,
                                           const float* __restrict__ pd,
                                           u32* __restrict__ mqlo,
                                           u32* __restrict__ mqhi,
                                           u32* __restrict__ mslot,
                                           u32* __restrict__ prefT2) {
    __shared__ u32 smem[12608];    // 50.4 KB
    u32* cntinv = smem;            // [1564]
    u32* nkw    = smem + 1564;     // [1564]
    u32* sstart = smem + 3128;     // [256]
    u32* spref  = smem + 3384;     // [257]
    u32* lcnt2  = smem + 3641;     // [256]
    u32* pref2  = smem + 3897;     // [257]
    u32* rQlo   = smem + 4160;     // [2816]
    u32* rQhi   = smem + 6976;     // [2816]
    u32* rSl    = smem + 9792;     // [2816]
    const int tid = threadIdx.x;
    const int b = blockIdx.x;
    const int lo = b * WID;

    for (int i = tid; i < WID; i += 1024) cntinv[i] = 0u;
    if (tid < 256) {
        u32 a = prefT1[tid * 257 + b];
        u32 c2 = prefT1[tid * 257 + b + 1];
        sstart[tid] = a; spref[tid + 1] = c2 - a; lcnt2[tid] = 0u;
    }
    if (tid == 0) spref[0] = 0u;
    __syncthreads();
    for (int off = 1; off < 256; off <<= 1) {
        u32 add = 0;
        if (tid < 256 && tid >= off) add = spref[tid - off + 1];
        __syncthreads();
        if (tid < 256) spref[tid + 1] += add;
        __syncthreads();
    }
    const u32 total = spref[256];

    // pass 1: search once, load meta once (nt), count per-ls; cache for pass 2
    u32 pwv[3]; u32 gidx[3]; u32 valid[3];
#pragma unroll
    for (int it = 0; it < 3; ++it) {
        valid[it] = 0u;
        u32 i = (u32)(it * 1024 + tid);
        if (i < total) {
            int l2 = 0, h2 = 256;
            while (h2 - l2 > 1) {
                int mid = (l2 + h2) >> 1;
                if (spref[mid] <= i) l2 = mid; else h2 = mid;
            }
            u32 idx = (u32)l2 * EPB1 + sstart[l2] + (i - spref[l2]);
            u32 p = __builtin_nontemporal_load(&sme[idx]);
            atomicAdd(&cntinv[p & 0x7ffu], 1u);
            pwv[it] = p; gidx[it] = idx; valid[it] = 1u;
        }
    }
    // window node|kk (coalesced, cached)
    for (int i = tid; i < WID; i += 1024) {
        int ls = lo + i;
        u32 nk = 0u;
        if (ls < N_G_EDGES)
            nk = (u32)(u16)gsrc[ls] | ((u32)kk8[ls] << 16);
        nkw[i] = nk;
    }
    __syncthreads();
    for (int i = tid; i < WID; i += 1024) {
        u32 c = cntinv[i];
        cntinv[i] = __float_as_uint(1.0f / (float)(c < 1u ? 1u : c));
    }
    __syncthreads();

    // Taylor coeffs (R9-R11-proven)
    float A0[4], A1[4], A2[4], DD[4];
#pragma unroll
    for (int h = 0; h < 4; ++h) {
        float a = pa[h], B = fmodf(pb[h], PI_F), c = pc[h], d = pd[h];
        float K = a * HPI_F + B;
        float ck = cosf(K), sk = sinf(K);
        float u0 = 0.5f * (1.0f + ck);
        float f0 = powf(u0, c);
        float g1v = (-0.5f * a * sk) / u0;
        float u2 = -0.25f * a * a * ck;
        float g2v = u2 / u0 - 0.5f * g1v * g1v;
        A0[h] = f0;
        A1[h] = f0 * c * g1v;
        A2[h] = f0 * (c * g2v + 0.5f * c * c * g1v * g1v);
        DD[h] = d;
    }

    u64 qv[3]; u32 mv2[3];
#pragma unroll
    for (int it = 0; it < 3; ++it) {
        mv2[it] = 0u;
        if (valid[it]) {
            u32 p = pwv[it];
            u32 idx = gidx[it];
            float ct = __uint_as_float(__builtin_nontemporal_load(&sct[idx]));
            float dn = __uint_as_float(__builtin_nontemporal_load(&sdn[idx]));
            u32 li = p & 0x7ffu;
            u32 ld = p >> 11;
            float inv = __uint_as_float(cntinv[li]);
            u32 nk = nkw[li];
            int node = (int)(nk & 0xffffu);
            u32 kw = (nk >> 16) & 0xffu;
            int ka = (int)(kw & 0xfu);
            int kb = (int)(kw >> 4);
            int kd = kk8[ld] >> 4;               // cached gather, L2-protected by nt
            int key = ((ka == kd) ? 2 : 0) + ((kb == ka && kb == kd) ? 1 : 0);
            ct = fminf(fmaxf(ct, -EPSV), EPSV);
            float del = -ct;
            float dn2 = dn * dn;
            float s = inv * FXSCALE;
            u64 q = 0;
#pragma unroll
            for (int h = 0; h < 4; ++h) {
                float ang = A0[h] + del * (A1[h] + del * A2[h]);
                float rad = __expf(-DD[h] * dn2);
                q |= (u64)(u32)(ang * rad * s + 0.5f) << (16 * h);
            }
            u32 nb = (u32)node / NPB;
            u32 slot = ((u32)node - nb * NPB) * 4u + (u32)key;
            u32 rank = atomicAdd(&lcnt2[nb], 1u);
            qv[it] = q;
            mv2[it] = 0x80000000u | (rank << 18) | (nb << 10) | slot;
        }
    }
    __syncthreads();
    if (tid < 256) pref2[tid + 1] = lcnt2[tid];
    if (tid == 0) pref2[0] = 0u;
    __syncthreads();
    for (int off = 1; off < 256; off <<= 1) {
        u32 add = 0;
        if (tid < 256 && tid >= off) add = pref2[tid - off + 1];
        __syncthreads();
        if (tid < 256) pref2[tid + 1] += add;
        __syncthreads();
    }
#pragma unroll
    for (int it = 0; it < 3; ++it) {
        if (mv2[it] & 0x80000000u) {
            u32 nb = (mv2[it] >> 10) & 0xffu;
            u32 pos = pref2[nb] + ((mv2[it] >> 18) & 0x1fffu);
            if (pos < CAP2) {
                rQlo[pos] = (u32)qv[it];
                rQhi[pos] = (u32)(qv[it] >> 32);
                rSl[pos] = mv2[it] & 0x3ffu;
            }
        }
    }
    __syncthreads();
    u32 t2 = pref2[256]; if (t2 > CAP2) t2 = CAP2;
    for (u32 i = tid; i < t2; i += 1024) {
        __builtin_nontemporal_store(rQlo[i], &mqlo[(size_t)b * CAP2 + i]);
        __builtin_nontemporal_store(rQhi[i], &mqhi[(size_t)b * CAP2 + i]);
        __builtin_nontemporal_store(rSl[i],  &mslot[(size_t)b * CAP2 + i]);
    }
    if (tid <= 256) {
        u32 v = pref2[tid];
        prefT2[b * 257 + tid] = (v < CAP2) ? v : CAP2;
    }
}

// ============ k3: per node-bucket gather + invg + fused output ============
__global__ __launch_bounds__(1024) void k3(const u32* __restrict__ mqlo,
                                           const u32* __restrict__ mqhi,
                                           const u32* __restrict__ mslot,
                                           const u32* __restrict__ prefT2,
                                           const u32* __restrict__ cg,
                                           const float* __restrict__ VT,
                                           float* __restrict__ out) {
    __shared__ u32 smem[3328];
    u64* ts     = (u64*)smem;            // [784] = 1568 words
    float* vt_s = (float*)(smem + 1568); // [1024]
    float* ivg  = (float*)(smem + 2592); // [196]
    u32* sstart = smem + 2788;           // [256]
    u32* spref  = smem + 3044;           // [257]
    const int tid = threadIdx.x;
    const int nb = blockIdx.x;

    for (int i = tid; i < SPB; i += 1024) ts[i] = 0ull;
    vt_s[tid] = VT[tid];
    if (tid < NPB) {
        int n = nb * NPB + tid;
        float iv = 0.0f;
        if (n < N_NODES) {
            int w = n >> 2, sh = 8 * (n & 3);
            u32 c = 0;
#pragma unroll
            for (int cc = 0; cc < GH_N; ++cc)
                c += (cg[cc * GH_W + w] >> sh) & 0xffu;
            iv = 1.0f / (float)(c < 1u ? 1u : c);
        }
        ivg[tid] = iv;
    }
    if (tid < 256) {
        u32 a = prefT2[tid * 257 + nb];
        u32 c2 = prefT2[tid * 257 + nb + 1];
        sstart[tid] = a; spref[tid + 1] = c2 - a;
    }
    if (tid == 0) spref[0] = 0u;
    __syncthreads();
    for (int off = 1; off < 256; off <<= 1) {
        u32 add = 0;
        if (tid < 256 && tid >= off) add = spref[tid - off + 1];
        __syncthreads();
        if (tid < 256) spref[tid + 1] += add;
        __syncthreads();
    }
    const u32 total = spref[256];

    for (u32 i = tid; i < total; i += 1024) {
        int l2 = 0, h2 = 256;
        while (h2 - l2 > 1) {
            int mid = (l2 + h2) >> 1;
            if (spref[mid] <= i) l2 = mid; else h2 = mid;
        }
        size_t idx = (size_t)l2 * CAP2 + sstart[l2] + (i - spref[l2]);
        u64 q = (u64)__builtin_nontemporal_load(&mqlo[idx])
              | ((u64)__builtin_nontemporal_load(&mqhi[idx]) << 32);
        atomicAdd(&ts[__builtin_nontemporal_load(&mslot[idx])], q);
    }
    __syncthreads();

    const int n0 = nb * NPB;
    for (int j = tid; j < NPB * OUT_FEATS; j += 1024) {
        int nl = j >> 6, f = j & 63;
        int n = n0 + nl;
        if (n < N_NODES) {
            float acc = 0.0f;
#pragma unroll
            for (int k = 0; k < 4; ++k) {
                u64 t = ts[nl * 4 + k];
#pragma unroll
                for (int h = 0; h < 4; ++h) {
                    float tv = (float)((u32)(t >> (16 * h)) & 0xffffu);
                    acc += vt_s[k * 256 + f * 4 + h] * tv;
                }
            }
            __builtin_nontemporal_store(acc * INV_FXSCALE * ivg[nl],
                                        &out[n * OUT_FEATS + f]);
        }
    }
}

extern "C" void kernel_launch(void* const* d_in, const int* in_sizes, int n_in,
                              void* d_out, int out_size, void* d_ws, size_t ws_size,
                              hipStream_t stream) {
    const int*   an       = (const int*)d_in[0];
    const int*   gsrc     = (const int*)d_in[1];
    const int*   gdst     = (const int*)d_in[2];
    const int*   lgsrc    = (const int*)d_in[3];
    const int*   lgdst    = (const int*)d_in[4];
    const float* costheta = (const float*)d_in[5];
    const float* dnr      = (const float*)d_in[6];
    const float* pa       = (const float*)d_in[7];
    const float* pb       = (const float*)d_in[8];
    const float* pc       = (const float*)d_in[9];
    const float* pd       = (const float*)d_in[10];
    const float* vt       = (const float*)d_in[11];
    float* out = (float*)d_out;

    char* ws = (char*)d_ws;
    u8*  kk8    = (u8*) (ws + 0);
    u32* cg     = (u32*)(ws + 400000);
    u32* prefT1 = (u32*)(ws + 1200000);
    u32* prefT2 = (u32*)(ws + 1463168);
    u32* sme    = (u32*)(ws + 1726336);
    u32* sct    = (u32*)(ws + 4126592);
    u32* sdn    = (u32*)(ws + 6526848);
    u32* mqlo   = (u32*)(ws + 8927104);
    u32* mqhi   = (u32*)(ws + 11810688);
    u32* mslot  = (u32*)(ws + 14694272);

    k1<<<dim3(K1_GRID), dim3(1024), 0, stream>>>(
        an, gsrc, gdst, lgsrc, lgdst, costheta, dnr, kk8, cg, prefT1,
        sme, sct, sdn);
    k2<<<dim3(256), dim3(1024), 0, stream>>>(
        gsrc, kk8, prefT1, sme, sct, sdn, pa, pb, pc, pd,
        mqlo, mqhi, mslot, prefT2);
    k3<<<dim3(256), dim3(1024), 0, stream>>>(
        mqlo, mqhi, mslot, prefT2, cg, vt, out);
}

// Round 14
// 48.508 us; speedup vs baseline: 1.9808x; 1.0598x over previous
//
#include <hip/hip_runtime.h>
#include <math.h>

typedef unsigned long long u64;
typedef unsigned int u32;
typedef unsigned short u16;
typedef unsigned char u8;

#define N_NODES    50000
#define N_G_EDGES  400000
#define N_LG_EDGES 600000
#define OUT_FEATS  64
#define EPSV       0.001f
#define PI_F       3.14159265358979323846f
#define HPI_F      1.57079632679489662f
#define FXSCALE    512.0f
#define INV_FXSCALE (1.0f/512.0f)

#define CT_SCALE   3.2e7f
#define CT_INV     (1.0f/3.2e7f)
#define DN_SCALE   65535.0f
#define DN_INV     (1.0f/65535.0f)

// ---- k1 roles (384 blocks) ----
#define SB_N    256
#define EPB1    2344       // 256*2344 >= 600000
#define GH_B0   256
#define GH_N    16
#define GH_EPC  25000
#define GH_W    12500
#define PK_B0   272
#define PK_GPB  3572
#define K1_GRID 384

#define WID   1564         // ls-bucket width
#define NPB   196
#define SPB   (NPB*4)
#define CAP2  2816

// ws layout (bytes):
//   kk8    u8 [400000]    @ 0          (  400,000)
//   cg     u32[16*12500]  @ 400,000    (  800,000)
//   prefT1 u32[256*257]   @ 1,200,000  (  263,168)
//   prefT2 u32[256*257]   @ 1,463,168  (  263,168)
//   sme64  u64[256*2344]  @ 1,726,336  (4,800,512)
//   mq64   u64[256*2816]  @ 6,526,848  (5,767,168)
// total 12,294,016

// ============ k1: ls-bucket sort (u64 recs) + g-hist + kk8 pack ============
__global__ __launch_bounds__(1024) void k1(const int* __restrict__ an,
                                           const int* __restrict__ gsrc,
                                           const int* __restrict__ gdst,
                                           const int* __restrict__ lgsrc,
                                           const int* __restrict__ lgdst,
                                           const float* __restrict__ costheta,
                                           const float* __restrict__ dnr,
                                           u8*  __restrict__ kk8,
                                           u32* __restrict__ cg,
                                           u32* __restrict__ prefT1,
                                           u64* __restrict__ sme64) {
    __shared__ u64 sm64[6250];   // 50 KB union (hist view via u32*)
    const int tid = threadIdx.x;
    const int bid = blockIdx.x;

    if (bid < SB_N) {
        u64* metaS = sm64;                      // [2344]
        u32* lcnt  = (u32*)(sm64 + 2344);       // [256]
        u32* pref  = (u32*)(sm64 + 2344) + 256; // [257]
        if (tid < 256) lcnt[tid] = 0u;
        __syncthreads();

        const int e0 = bid * EPB1;
        const int e1 = (e0 + EPB1 < N_LG_EDGES) ? e0 + EPB1 : N_LG_EDGES;
        u64 pv[3]; u32 mv[3];
#pragma unroll
        for (int it = 0; it < 3; ++it) {
            mv[it] = 0u;
            int e = e0 + it * 1024 + tid;
            if (e < e1) {
                int ls = __builtin_nontemporal_load(&lgsrc[e]);
                int ld = __builtin_nontemporal_load(&lgdst[e]);
                float ct = __builtin_nontemporal_load(&costheta[e]);
                float dn = __builtin_nontemporal_load(&dnr[e]);
                // quantize: ct clipped to [-1e-3,1e-3] -> 16b; dn [0,1) -> 16b
                float cc = fminf(fmaxf(ct, -EPSV), EPSV);
                u32 ct16 = (u32)(u16)(cc * CT_SCALE + 32768.0f + 0.5f);
                float dns = dn * DN_SCALE + 0.5f;
                u32 dn16 = (u32)(dns < 65535.0f ? (u16)dns : (u16)65535u);
                u32 bk = (u32)ls / WID;
                u32 li = (u32)ls - bk * WID;
                pv[it] = (u64)li | ((u64)(u32)ld << 11) | ((u64)dn16 << 30)
                       | ((u64)ct16 << 46);
                u32 rank = atomicAdd(&lcnt[bk], 1u);
                mv[it] = 0x80000000u | (rank << 8) | bk;
            }
        }
        __syncthreads();
        if (tid < 256) pref[tid + 1] = lcnt[tid];
        if (tid == 0) pref[0] = 0u;
        __syncthreads();
        for (int off = 1; off < 256; off <<= 1) {
            u32 add = 0;
            if (tid < 256 && tid >= off) add = pref[tid - off + 1];
            __syncthreads();
            if (tid < 256) pref[tid + 1] += add;
            __syncthreads();
        }
#pragma unroll
        for (int it = 0; it < 3; ++it) {
            if (mv[it] & 0x80000000u) {
                u32 bk = mv[it] & 0xffu;
                u32 pos = pref[bk] + ((mv[it] >> 8) & 0x7fffffu);
                metaS[pos] = pv[it];
            }
        }
        __syncthreads();
        const u32 btot = pref[256];
        for (u32 i = tid; i < btot; i += 1024)
            __builtin_nontemporal_store(metaS[i], &sme64[(size_t)bid * EPB1 + i]);
        if (tid <= 256) prefT1[bid * 257 + tid] = pref[tid];
    } else if (bid < PK_B0) {
        u32* hist = (u32*)sm64;
        const int cc = bid - GH_B0;
        for (int w = tid; w < GH_W; w += 1024) hist[w] = 0u;
        __syncthreads();
        const int s0 = cc * GH_EPC;
        for (int g = s0 + tid; g < s0 + GH_EPC; g += 1024) {
            int n = gsrc[g];
            atomicAdd(&hist[n >> 2], 1u << (8 * (n & 3)));
        }
        __syncthreads();
        for (int w = tid; w < GH_W; w += 1024) cg[cc * GH_W + w] = hist[w];
    } else {
        const int g0 = (bid - PK_B0) * PK_GPB;
        const int g1 = (g0 + PK_GPB < N_G_EDGES) ? g0 + PK_GPB : N_G_EDGES;
        for (int g = g0 + tid; g < g1; g += 1024)
            kk8[g] = (u8)(an[gsrc[g]] | (an[gdst[g]] << 4));
    }
}

// ============ k2: stage -> count -> compute -> node-bucket sort ============
__global__ __launch_bounds__(1024) void k2(const int* __restrict__ gsrc,
                                           const u8*  __restrict__ kk8,
                                           const u32* __restrict__ prefT1,
                                           const u64* __restrict__ sme64,
                                           const float* __restrict__ pa,
                                           const float* __restrict__ pb,
                                           const float* __restrict__ pc,
                                           const float* __restrict__ pd,
                                           u64* __restrict__ mq64,
                                           u32* __restrict__ prefT2) {
    __shared__ u64 sm64[5632 + 78];             // stage[2816] + outst[2816] (+pad)
    __shared__ u32 su[4154];                    // u32 region
    u64* stage  = sm64;                         // [2816]
    u64* outst  = sm64 + 2816;                  // [2816]
    u32* cntinv = su;                           // [1564]
    u32* nkw    = su + 1564;                    // [1564]
    u32* sstart = su + 3128;                    // [256]
    u32* soff   = su + 3384;                    // [257]
    u32* lcnt2  = su + 3641;                    // [256]
    u32* pref2  = su + 3897;                    // [257]
    const int tid = threadIdx.x;
    const int b = blockIdx.x;
    const int lo = b * WID;

    for (int i = tid; i < WID; i += 1024) cntinv[i] = 0u;
    if (tid < 256) {
        u32 a = prefT1[tid * 257 + b];
        u32 c2 = prefT1[tid * 257 + b + 1];
        sstart[tid] = a; soff[tid + 1] = c2 - a; lcnt2[tid] = 0u;
    }
    if (tid == 0) soff[0] = 0u;
    __syncthreads();
    for (int off = 1; off < 256; off <<= 1) {
        u32 add = 0;
        if (tid < 256 && tid >= off) add = soff[tid - off + 1];
        __syncthreads();
        if (tid < 256) soff[tid + 1] += add;
        __syncthreads();
    }
    u32 total = soff[256]; if (total > CAP2) total = CAP2;

    // stage all records: 4 threads per source segment, contiguous copies
    {
        const int g = tid >> 2, lane = tid & 3;
        const u32 st = sstart[g];
        const u32 base = soff[g];
        const u32 len = soff[g + 1] - base;
        const u64* src = sme64 + (size_t)g * EPB1 + st;
        for (u32 j = lane; j < len; j += 4) {
            u32 p = base + j;
            if (p < CAP2) stage[p] = __builtin_nontemporal_load(&src[j]);
        }
    }
    // window node|kk (coalesced)
    for (int i = tid; i < WID; i += 1024) {
        int ls = lo + i;
        u32 nk = 0u;
        if (ls < N_G_EDGES)
            nk = (u32)(u16)gsrc[ls] | ((u32)kk8[ls] << 16);
        nkw[i] = nk;
    }
    __syncthreads();
    // count per-ls from staged records
    for (u32 i = tid; i < total; i += 1024)
        atomicAdd(&cntinv[(u32)(stage[i] & 0x7ffu)], 1u);
    __syncthreads();
    for (int i = tid; i < WID; i += 1024) {
        u32 c = cntinv[i];
        cntinv[i] = __float_as_uint(1.0f / (float)(c < 1u ? 1u : c));
    }
    __syncthreads();

    // Taylor coeffs (R9-R13-proven)
    float A0[4], A1[4], A2[4], DD[4];
#pragma unroll
    for (int h = 0; h < 4; ++h) {
        float a = pa[h], B = fmodf(pb[h], PI_F), c = pc[h], d = pd[h];
        float K = a * HPI_F + B;
        float ck = cosf(K), sk = sinf(K);
        float u0 = 0.5f * (1.0f + ck);
        float f0 = powf(u0, c);
        float g1v = (-0.5f * a * sk) / u0;
        float u2 = -0.25f * a * a * ck;
        float g2v = u2 / u0 - 0.5f * g1v * g1v;
        A0[h] = f0;
        A1[h] = f0 * c * g1v;
        A2[h] = f0 * (c * g2v + 0.5f * c * c * g1v * g1v);
        DD[h] = d;
    }

    u64 qv[3]; u32 mv2[3];
#pragma unroll
    for (int it = 0; it < 3; ++it) {
        mv2[it] = 0u;
        u32 i = (u32)(it * 1024 + tid);
        if (i < total) {
            u64 v = stage[i];
            u32 li = (u32)(v & 0x7ffu);
            u32 ld = (u32)((v >> 11) & 0x7ffffu);
            float dn = (float)(u32)((v >> 30) & 0xffffu) * DN_INV;
            float ct = ((float)(u32)((v >> 46) & 0xffffu) - 32768.0f) * CT_INV;
            float inv = __uint_as_float(cntinv[li]);
            u32 nk = nkw[li];
            int node = (int)(nk & 0xffffu);
            u32 kw = (nk >> 16) & 0xffu;
            int ka = (int)(kw & 0xfu);
            int kb = (int)(kw >> 4);
            int kd = kk8[ld] >> 4;
            int key = ((ka == kd) ? 2 : 0) + ((kb == ka && kb == kd) ? 1 : 0);
            float del = -ct;
            float dn2 = dn * dn;
            float s = inv * FXSCALE;
            u64 q = 0;
#pragma unroll
            for (int h = 0; h < 4; ++h) {
                float ang = A0[h] + del * (A1[h] + del * A2[h]);
                float rad = __expf(-DD[h] * dn2);
                q |= (u64)(u32)(ang * rad * s + 0.5f) << (10 * h);
            }
            u32 nb = (u32)node / NPB;
            u32 slot = ((u32)node - nb * NPB) * 4u + (u32)key;
            u32 rank = atomicAdd(&lcnt2[nb], 1u);
            qv[it] = (q << 10) | (u64)slot;       // mrec: slot[0:9], q_h at 10+10h
            mv2[it] = 0x80000000u | (rank << 18) | (nb << 10);
        }
    }
    __syncthreads();
    if (tid < 256) pref2[tid + 1] = lcnt2[tid];
    if (tid == 0) pref2[0] = 0u;
    __syncthreads();
    for (int off = 1; off < 256; off <<= 1) {
        u32 add = 0;
        if (tid < 256 && tid >= off) add = pref2[tid - off + 1];
        __syncthreads();
        if (tid < 256) pref2[tid + 1] += add;
        __syncthreads();
    }
#pragma unroll
    for (int it = 0; it < 3; ++it) {
        if (mv2[it] & 0x80000000u) {
            u32 nb = (mv2[it] >> 10) & 0xffu;
            u32 pos = pref2[nb] + ((mv2[it] >> 18) & 0x1fffu);
            if (pos < CAP2) outst[pos] = qv[it];
        }
    }
    __syncthreads();
    u32 t2 = pref2[256]; if (t2 > CAP2) t2 = CAP2;
    for (u32 i = tid; i < t2; i += 1024)
        __builtin_nontemporal_store(outst[i], &mq64[(size_t)b * CAP2 + i]);
    if (tid <= 256) {
        u32 v = pref2[tid];
        prefT2[b * 257 + tid] = (v < CAP2) ? v : CAP2;
    }
}

// ============ k3: stage -> LDS accumulate -> fused output ============
__global__ __launch_bounds__(1024) void k3(const u64* __restrict__ mq64,
                                           const u32* __restrict__ prefT2,
                                           const u32* __restrict__ cg,
                                           const float* __restrict__ VT,
                                           float* __restrict__ out) {
    __shared__ u64 sm64[2816 + 784];     // stage + ts
    __shared__ u32 su[2506];
    u64* stage  = sm64;                  // [2816]
    u64* ts     = sm64 + 2816;           // [784]
    float* vt_s = (float*)su;            // [1024]
    float* ivg  = (float*)(su + 1024);   // [196]
    u32* sstart = su + 1220;             // [256]
    u32* soff   = su + 1476;             // [257]
    const int tid = threadIdx.x;
    const int nb = blockIdx.x;

    for (int i = tid; i < SPB; i += 1024) ts[i] = 0ull;
    vt_s[tid] = VT[tid];
    if (tid < NPB) {
        int n = nb * NPB + tid;
        float iv = 0.0f;
        if (n < N_NODES) {
            int w = n >> 2, sh = 8 * (n & 3);
            u32 c = 0;
#pragma unroll
            for (int cc = 0; cc < GH_N; ++cc)
                c += (cg[cc * GH_W + w] >> sh) & 0xffu;
            iv = 1.0f / (float)(c < 1u ? 1u : c);
        }
        ivg[tid] = iv;
    }
    if (tid < 256) {
        u32 a = prefT2[tid * 257 + nb];
        u32 c2 = prefT2[tid * 257 + nb + 1];
        sstart[tid] = a; soff[tid + 1] = c2 - a;
    }
    if (tid == 0) soff[0] = 0u;
    __syncthreads();
    for (int off = 1; off < 256; off <<= 1) {
        u32 add = 0;
        if (tid < 256 && tid >= off) add = soff[tid - off + 1];
        __syncthreads();
        if (tid < 256) soff[tid + 1] += add;
        __syncthreads();
    }
    u32 total = soff[256]; if (total > CAP2) total = CAP2;

    // stage: 4 threads per source-bucket segment
    {
        const int g = tid >> 2, lane = tid & 3;
        const u32 st = sstart[g];
        const u32 base = soff[g];
        const u32 len = soff[g + 1] - base;
        const u64* src = mq64 + (size_t)g * CAP2 + st;
        for (u32 j = lane; j < len; j += 4) {
            u32 p = base + j;
            if (p < CAP2) stage[p] = __builtin_nontemporal_load(&src[j]);
        }
    }
    __syncthreads();

    for (u32 i = tid; i < total; i += 1024) {
        u64 v = stage[i];
        u32 slot = (u32)(v & 0x3ffu);
        u64 q = ((v >> 10) & 0x3ffu) | (((v >> 20) & 0x3ffu) << 16)
              | (((v >> 30) & 0x3ffu) << 32) | (((v >> 40) & 0x3ffu) << 48);
        atomicAdd(&ts[slot], q);
    }
    __syncthreads();

    const int n0 = nb * NPB;
    for (int j = tid; j < NPB * OUT_FEATS; j += 1024) {
        int nl = j >> 6, f = j & 63;
        int n = n0 + nl;
        if (n < N_NODES) {
            float acc = 0.0f;
#pragma unroll
            for (int k = 0; k < 4; ++k) {
                u64 t = ts[nl * 4 + k];
#pragma unroll
                for (int h = 0; h < 4; ++h) {
                    float tv = (float)((u32)(t >> (16 * h)) & 0xffffu);
                    acc += vt_s[k * 256 + f * 4 + h] * tv;
                }
            }
            __builtin_nontemporal_store(acc * INV_FXSCALE * ivg[nl],
                                        &out[n * OUT_FEATS + f]);
        }
    }
}

extern "C" void kernel_launch(void* const* d_in, const int* in_sizes, int n_in,
                              void* d_out, int out_size, void* d_ws, size_t ws_size,
                              hipStream_t stream) {
    const int*   an       = (const int*)d_in[0];
    const int*   gsrc     = (const int*)d_in[1];
    const int*   gdst     = (const int*)d_in[2];
    const int*   lgsrc    = (const int*)d_in[3];
    const int*   lgdst    = (const int*)d_in[4];
    const float* costheta = (const float*)d_in[5];
    const float* dnr      = (const float*)d_in[6];
    const float* pa       = (const float*)d_in[7];
    const float* pb       = (const float*)d_in[8];
    const float* pc       = (const float*)d_in[9];
    const float* pd       = (const float*)d_in[10];
    const float* vt       = (const float*)d_in[11];
    float* out = (float*)d_out;

    char* ws = (char*)d_ws;
    u8*  kk8    = (u8*) (ws + 0);
    u32* cg     = (u32*)(ws + 400000);
    u32* prefT1 = (u32*)(ws + 1200000);
    u32* prefT2 = (u32*)(ws + 1463168);
    u64* sme64  = (u64*)(ws + 1726336);
    u64* mq64   = (u64*)(ws + 6526848);

    k1<<<dim3(K1_GRID), dim3(1024), 0, stream>>>(
        an, gsrc, gdst, lgsrc, lgdst, costheta, dnr, kk8, cg, prefT1, sme64);
    k2<<<dim3(256), dim3(1024), 0, stream>>>(
        gsrc, kk8, prefT1, sme64, pa, pb, pc, pd, mq64, prefT2);
    k3<<<dim3(256), dim3(1024), 0, stream>>>(
        mq64, prefT2, cg, vt, out);
}